// Round 1
// baseline (435.106 us; speedup 1.0000x reference)
//
#include <hip/hip_runtime.h>
#include <math.h>

namespace {

constexpr int Bb = 2, Ll = 2048, Dd = 512, Hh = 8, HD = 64;
constexpr int M = Bb * Ll;        // 4096 rows total
constexpr int THREE_D = 3 * Dd;   // 1536

// ---------------------------------------------------------------------------
// Tiled GEMM: C[M,N] = A[M,K] @ W[N,K]^T + bias[N] (+ optional residual R)
// 64x64 output tile per block, 256 threads, 4x4 register tile per thread.
// LDS tiles stored transposed ([kk][row]) so inner loop uses ds_read_b128.
// ---------------------------------------------------------------------------
template <int K, bool ADD_RES>
__global__ __launch_bounds__(256) void gemm_bias(
    const float* __restrict__ A, const float* __restrict__ W,
    const float* __restrict__ bias, const float* __restrict__ R,
    float* __restrict__ C, int N) {
  __shared__ float As[64][68];  // As[kk][row]  (transposed)
  __shared__ float Ws[64][68];  // Ws[kk][col]  (transposed)

  const int tid = threadIdx.x;
  const int tx = tid & 15;   // 0..15 -> 4 output cols each
  const int ty = tid >> 4;   // 0..15 -> 4 output rows each
  const int m0 = blockIdx.y * 64;
  const int n0 = blockIdx.x * 64;

  float acc[4][4] = {};

  for (int k0 = 0; k0 < K; k0 += 64) {
#pragma unroll
    for (int p = 0; p < 4; ++p) {
      const int row = ty + p * 16;
      const int col = tx * 4;
      float4 a = *reinterpret_cast<const float4*>(
          &A[(size_t)(m0 + row) * K + k0 + col]);
      float4 w = *reinterpret_cast<const float4*>(
          &W[(size_t)(n0 + row) * K + k0 + col]);
      As[col + 0][row] = a.x; As[col + 1][row] = a.y;
      As[col + 2][row] = a.z; As[col + 3][row] = a.w;
      Ws[col + 0][row] = w.x; Ws[col + 1][row] = w.y;
      Ws[col + 2][row] = w.z; Ws[col + 3][row] = w.w;
    }
    __syncthreads();

#pragma unroll 8
    for (int kk = 0; kk < 64; ++kk) {
      float4 a4 = *reinterpret_cast<const float4*>(&As[kk][ty * 4]);
      float4 w4 = *reinterpret_cast<const float4*>(&Ws[kk][tx * 4]);
      const float av[4] = {a4.x, a4.y, a4.z, a4.w};
      const float wv[4] = {w4.x, w4.y, w4.z, w4.w};
#pragma unroll
      for (int r = 0; r < 4; ++r)
#pragma unroll
        for (int c = 0; c < 4; ++c)
          acc[r][c] = fmaf(av[r], wv[c], acc[r][c]);
    }
    __syncthreads();
  }

#pragma unroll
  for (int r = 0; r < 4; ++r) {
    const int m = m0 + ty * 4 + r;
#pragma unroll
    for (int c = 0; c < 4; ++c) {
      const int n = n0 + tx * 4 + c;
      float v = acc[r][c] + bias[n];
      if (ADD_RES) v += R[(size_t)m * N + n];
      C[(size_t)m * N + n] = v;
    }
  }
}

// ---------------------------------------------------------------------------
// Fused attention (flash-style, anti-local mask): one block per
// (b, h, 64-row q tile). 256 threads, 4x4 register tiles for S and O.
// Mask: banned (=-inf) iff  i-half <= j < i+half.
// ---------------------------------------------------------------------------
__global__ __launch_bounds__(256) void attn_kernel(
    const float* __restrict__ qkv, const int* __restrict__ wsz,
    float* __restrict__ ctx) {
  __shared__ float Qs[64][68];  // Qs[d][row]  (transposed, pre-scaled)
  __shared__ float Ks[64][68];  // Ks[d][col]  (transposed); later reused as P
  __shared__ float Vs[64][68];  // Vs[j][d]    (natural)
  float(*Ps)[68] = Ks;          // P[i][j] aliases Ks (K dead after S compute)

  const int tid = threadIdx.x;
  const int tx = tid & 15;
  const int ty = tid >> 4;
  const int qt = blockIdx.x & 31;
  const int h = (blockIdx.x >> 5) & 7;
  const int b = blockIdx.x >> 8;
  const int qbase = qt * 64;
  const int half = wsz[0] / 2;

  const float* base = qkv + (size_t)b * Ll * THREE_D + (size_t)h * HD;

  // stage Q tile once, scaled by 1/sqrt(hd)=0.125
#pragma unroll
  for (int p = 0; p < 4; ++p) {
    const int row = ty + p * 16;
    const int col = tx * 4;
    float4 q = *reinterpret_cast<const float4*>(
        &base[(size_t)(qbase + row) * THREE_D + col]);
    Qs[col + 0][row] = q.x * 0.125f;
    Qs[col + 1][row] = q.y * 0.125f;
    Qs[col + 2][row] = q.z * 0.125f;
    Qs[col + 3][row] = q.w * 0.125f;
  }

  float o[4][4] = {};
  float mrow[4] = {-1e30f, -1e30f, -1e30f, -1e30f};
  float lrow[4] = {0.f, 0.f, 0.f, 0.f};

  for (int kt = 0; kt < Ll / 64; ++kt) {
    const int kbase = kt * 64;
    __syncthreads();  // prev iter done with Ks(P)/Vs; Q staged (iter 0)

#pragma unroll
    for (int p = 0; p < 4; ++p) {
      const int row = ty + p * 16;
      const int col = tx * 4;
      float4 k = *reinterpret_cast<const float4*>(
          &base[(size_t)(kbase + row) * THREE_D + Dd + col]);
      float4 v = *reinterpret_cast<const float4*>(
          &base[(size_t)(kbase + row) * THREE_D + 2 * Dd + col]);
      Ks[col + 0][row] = k.x; Ks[col + 1][row] = k.y;
      Ks[col + 2][row] = k.z; Ks[col + 3][row] = k.w;
      *reinterpret_cast<float4*>(&Vs[row][col]) = v;
    }
    __syncthreads();

    // S = Q K^T  (per-thread 4x4)
    float s[4][4] = {};
#pragma unroll 8
    for (int kk = 0; kk < 64; ++kk) {
      float4 q4 = *reinterpret_cast<const float4*>(&Qs[kk][ty * 4]);
      float4 k4 = *reinterpret_cast<const float4*>(&Ks[kk][tx * 4]);
      const float qv[4] = {q4.x, q4.y, q4.z, q4.w};
      const float kv[4] = {k4.x, k4.y, k4.z, k4.w};
#pragma unroll
      for (int r = 0; r < 4; ++r)
#pragma unroll
        for (int c = 0; c < 4; ++c) s[r][c] = fmaf(qv[r], kv[c], s[r][c]);
    }

    // anti-local mask
#pragma unroll
    for (int r = 0; r < 4; ++r) {
      const int ig = qbase + ty * 4 + r;
#pragma unroll
      for (int c = 0; c < 4; ++c) {
        const int jg = kbase + tx * 4 + c;
        if (jg >= ig - half && jg < ig + half) s[r][c] = -1e30f;
      }
    }

    __syncthreads();  // all S reads of Ks done before P overwrites it

    // online softmax per row (rows span 16 consecutive lanes)
#pragma unroll
    for (int r = 0; r < 4; ++r) {
      float mloc = fmaxf(fmaxf(s[r][0], s[r][1]), fmaxf(s[r][2], s[r][3]));
#pragma unroll
      for (int off = 1; off < 16; off <<= 1)
        mloc = fmaxf(mloc, __shfl_xor(mloc, off, 16));
      const float mnew = fmaxf(mrow[r], mloc);
      float p0 = __expf(s[r][0] - mnew);
      float p1 = __expf(s[r][1] - mnew);
      float p2 = __expf(s[r][2] - mnew);
      float p3 = __expf(s[r][3] - mnew);
      float lsum = (p0 + p1) + (p2 + p3);
#pragma unroll
      for (int off = 1; off < 16; off <<= 1)
        lsum += __shfl_xor(lsum, off, 16);
      const float corr = __expf(mrow[r] - mnew);
      lrow[r] = lrow[r] * corr + lsum;
      mrow[r] = mnew;
#pragma unroll
      for (int c = 0; c < 4; ++c) o[r][c] *= corr;
      float4 pv = make_float4(p0, p1, p2, p3);
      *reinterpret_cast<float4*>(&Ps[ty * 4 + r][tx * 4]) = pv;
    }
    __syncthreads();

    // O += P V
#pragma unroll 8
    for (int j = 0; j < 64; ++j) {
      float4 v4 = *reinterpret_cast<const float4*>(&Vs[j][tx * 4]);
      const float vv[4] = {v4.x, v4.y, v4.z, v4.w};
      float pr[4];
#pragma unroll
      for (int r = 0; r < 4; ++r) pr[r] = Ps[ty * 4 + r][j];
#pragma unroll
      for (int r = 0; r < 4; ++r)
#pragma unroll
        for (int c = 0; c < 4; ++c) o[r][c] = fmaf(pr[r], vv[c], o[r][c]);
    }
  }

  // epilogue: normalize and write ctx[b, row, h*64 + d]
#pragma unroll
  for (int r = 0; r < 4; ++r) {
    const float inv = 1.0f / lrow[r];
    const int row = qbase + ty * 4 + r;
    float4 outv = make_float4(o[r][0] * inv, o[r][1] * inv, o[r][2] * inv,
                              o[r][3] * inv);
    *reinterpret_cast<float4*>(
        &ctx[((size_t)b * Ll + row) * Dd + h * HD + tx * 4]) = outv;
  }
}

// ---------------------------------------------------------------------------
// Row LayerNorm: one block per row of y[4096, 512]
// ---------------------------------------------------------------------------
__global__ __launch_bounds__(256) void ln_kernel(
    const float* __restrict__ y, const float* __restrict__ gamma,
    const float* __restrict__ beta, float* __restrict__ out) {
  const int row = blockIdx.x;
  const int tid = threadIdx.x;
  const float* yr = y + (size_t)row * Dd;

  float2 v = *reinterpret_cast<const float2*>(&yr[tid * 2]);
  float s = v.x + v.y;
  float q = v.x * v.x + v.y * v.y;
#pragma unroll
  for (int off = 1; off < 64; off <<= 1) {
    s += __shfl_xor(s, off, 64);
    q += __shfl_xor(q, off, 64);
  }
  __shared__ float ss[4], qs[4];
  if ((tid & 63) == 0) {
    ss[tid >> 6] = s;
    qs[tid >> 6] = q;
  }
  __syncthreads();
  s = (ss[0] + ss[1]) + (ss[2] + ss[3]);
  q = (qs[0] + qs[1]) + (qs[2] + qs[3]);

  const float mu = s * (1.0f / Dd);
  const float var = q * (1.0f / Dd) - mu * mu;
  const float rstd = rsqrtf(var + 1e-5f);

  float2 g = *reinterpret_cast<const float2*>(&gamma[tid * 2]);
  float2 be = *reinterpret_cast<const float2*>(&beta[tid * 2]);
  float2 o;
  o.x = (v.x - mu) * rstd * g.x + be.x;
  o.y = (v.y - mu) * rstd * g.y + be.y;
  *reinterpret_cast<float2*>(&out[(size_t)row * Dd + tid * 2]) = o;
}

}  // namespace

extern "C" void kernel_launch(void* const* d_in, const int* in_sizes, int n_in,
                              void* d_out, int out_size, void* d_ws,
                              size_t ws_size, hipStream_t stream) {
  const float* x = (const float*)d_in[0];
  const float* w_in = (const float*)d_in[1];
  const float* b_in = (const float*)d_in[2];
  const float* w_out = (const float*)d_in[3];
  const float* b_out = (const float*)d_in[4];
  const float* gamma = (const float*)d_in[5];
  const float* beta = (const float*)d_in[6];
  const int* wsz = (const int*)d_in[7];
  float* out = (float*)d_out;

  float* qkv = (float*)d_ws;                      // [4096, 1536]  25.2 MB
  float* ctx = qkv + (size_t)M * THREE_D;         // [4096, 512]    8.4 MB
  float* y = qkv;                                 // reuse qkv region

  dim3 blk(256);

  // 1) qkv = x @ in_proj_w^T + in_proj_b
  gemm_bias<512, false><<<dim3(THREE_D / 64, M / 64), blk, 0, stream>>>(
      x, w_in, b_in, nullptr, qkv, THREE_D);

  // 2) fused masked attention -> ctx
  attn_kernel<<<dim3(Bb * Hh * (Ll / 64)), blk, 0, stream>>>(qkv, wsz, ctx);

  // 3) y = x + ctx @ out_proj_w^T + out_proj_b
  gemm_bias<512, true><<<dim3(Dd / 64, M / 64), blk, 0, stream>>>(
      ctx, w_out, b_out, x, y, Dd);

  // 4) out = LayerNorm(y) * gamma + beta
  ln_kernel<<<dim3(M), blk, 0, stream>>>(y, gamma, beta, out);
}

// Round 2
// 223.710 us; speedup vs baseline: 1.9450x; 1.9450x over previous
//
#include <hip/hip_runtime.h>
#include <hip/hip_bf16.h>
#include <math.h>

namespace {

constexpr int Bb = 2, Ll = 2048, Dd = 512, Hh = 8;
constexpr int M = Bb * Ll;       // 4096
constexpr int THREE_D = 3 * Dd;  // 1536

typedef __attribute__((ext_vector_type(8))) short short8;
typedef __attribute__((ext_vector_type(4))) short short4v;
typedef __attribute__((ext_vector_type(4))) float f32x4;

__device__ __forceinline__ unsigned short f2bf(float x) {
  union { __hip_bfloat16 h; unsigned short u; } cv;
  cv.h = __float2bfloat16(x);
  return cv.u;
}

__device__ __forceinline__ void gload_lds16(const void* g, void* l) {
  __builtin_amdgcn_global_load_lds(
      (const __attribute__((address_space(1))) void*)g,
      (__attribute__((address_space(3))) void*)l, 16, 0, 0);
}

// ---------------------------------------------------------------------------
// GEMM1: qkv[M,1536] = x[M,512] @ in_proj_w[1536,512]^T + b ; bf16 output,
// q-section (n<512) pre-scaled by 0.125 (exact in bf16).
// ---------------------------------------------------------------------------
__global__ __launch_bounds__(256) void gemm_qkv(
    const float* __restrict__ A, const float* __restrict__ W,
    const float* __restrict__ bias, unsigned short* __restrict__ C) {
  constexpr int K = 512;
  __shared__ float As[64][68];
  __shared__ float Ws[64][68];

  const int tid = threadIdx.x;
  const int tx = tid & 15;
  const int ty = tid >> 4;
  const int m0 = blockIdx.y * 64;
  const int n0 = blockIdx.x * 64;

  float acc[4][4] = {};

  for (int k0 = 0; k0 < K; k0 += 64) {
#pragma unroll
    for (int p = 0; p < 4; ++p) {
      const int row = ty + p * 16;
      const int col = tx * 4;
      float4 a = *reinterpret_cast<const float4*>(
          &A[(size_t)(m0 + row) * K + k0 + col]);
      float4 w = *reinterpret_cast<const float4*>(
          &W[(size_t)(n0 + row) * K + k0 + col]);
      As[col + 0][row] = a.x; As[col + 1][row] = a.y;
      As[col + 2][row] = a.z; As[col + 3][row] = a.w;
      Ws[col + 0][row] = w.x; Ws[col + 1][row] = w.y;
      Ws[col + 2][row] = w.z; Ws[col + 3][row] = w.w;
    }
    __syncthreads();
#pragma unroll 8
    for (int kk = 0; kk < 64; ++kk) {
      float4 a4 = *reinterpret_cast<const float4*>(&As[kk][ty * 4]);
      float4 w4 = *reinterpret_cast<const float4*>(&Ws[kk][tx * 4]);
      const float av[4] = {a4.x, a4.y, a4.z, a4.w};
      const float wv[4] = {w4.x, w4.y, w4.z, w4.w};
#pragma unroll
      for (int r = 0; r < 4; ++r)
#pragma unroll
        for (int c = 0; c < 4; ++c) acc[r][c] = fmaf(av[r], wv[c], acc[r][c]);
    }
    __syncthreads();
  }

#pragma unroll
  for (int r = 0; r < 4; ++r) {
    const int m = m0 + ty * 4 + r;
    const int nb = n0 + tx * 4;
    const float sc = (nb < Dd) ? 0.125f : 1.0f;  // 4-col group never crosses 512
    ushort4 pk;
    pk.x = f2bf((acc[r][0] + bias[nb + 0]) * sc);
    pk.y = f2bf((acc[r][1] + bias[nb + 1]) * sc);
    pk.z = f2bf((acc[r][2] + bias[nb + 2]) * sc);
    pk.w = f2bf((acc[r][3] + bias[nb + 3]) * sc);
    *reinterpret_cast<ushort4*>(&C[(size_t)m * THREE_D + nb]) = pk;
  }
}

// ---------------------------------------------------------------------------
// MFMA flash attention. Block = (b, h, 64 q-rows), 4 waves x 16 q-rows.
// K_lds: row-major [64][64] bf16 with byte ^= ((row&7)<<4) XOR swizzle.
// V_lds: tr-read subtile layout f(kv,d) = s*2048+n*512+g*128+jh*64+jj*16+q
//        (kv=32s+8g+4jh+jj, d=16n+q)  -> ds_read_b64_tr_b16 B-frags.
// P: per-wave col-major [64][16] bf16 -> tr-read A-frags.
// ---------------------------------------------------------------------------
__global__ __launch_bounds__(256) void attn_mfma(
    const unsigned short* __restrict__ qkv, const int* __restrict__ wsz,
    float* __restrict__ ctx) {
  __shared__ unsigned short Kls[4096];
  __shared__ unsigned short Vls[4096];
  __shared__ unsigned short Pls[4096];

  const int tid = threadIdx.x;
  const int lane = tid & 63;
  const int w = tid >> 6;
  const int wu = __builtin_amdgcn_readfirstlane(w);
  const int q = lane & 15;
  const int g = lane >> 4;

  const int qt = blockIdx.x & 31;
  const int h = (blockIdx.x >> 5) & 7;
  const int b = blockIdx.x >> 8;
  const int qbase = qt * 64;
  const int half = wsz[0] >> 1;

  const size_t bh_base = (size_t)b * Ll * THREE_D + h * 64;

  // Q A-frags: row = qbase + w*16 + q, k elem = 32s + 8g + j
  const unsigned short* qrow =
      qkv + bh_base + (size_t)(qbase + w * 16 + q) * THREE_D;
  const short8 qf0 = *reinterpret_cast<const short8*>(qrow + 8 * g);
  const short8 qf1 = *reinterpret_cast<const short8*>(qrow + 32 + 8 * g);

  // staging source offsets (loop-invariant parts)
  const int k_rowoff = w * 16 + (lane >> 3);
  const int k_dcol = 8 * ((lane & 7) ^ ((lane >> 3) & 7));
  const unsigned short* kg_base = qkv + bh_base + Dd + k_dcol;

  const int v_rowoff = 32 * (w >> 1) + 8 * ((lane >> 4) & 3) +
                       4 * ((lane >> 3) & 1) + ((lane >> 1) & 3);
  const unsigned short* vg_base = qkv + bh_base + 2 * Dd + 8 * (lane & 1);

  unsigned short* kls_w = &Kls[wu * 1024];
  unsigned short* vls_w = &Vls[wu * 1024];
  unsigned short* pw = &Pls[wu * 1024];

  f32x4 oacc[4] = {};
  float mrow[4], lrow[4];
#pragma unroll
  for (int r = 0; r < 4; ++r) { mrow[r] = -1e30f; lrow[r] = 0.f; }

  const int qlo = qbase + w * 16;

  for (int kt = 0; kt < Ll / 64; ++kt) {
    const int kbase = kt * 64;
    __syncthreads();  // prior tile's readers done

    gload_lds16(kg_base + (size_t)(kbase + k_rowoff) * THREE_D, kls_w);
    gload_lds16(kg_base + (size_t)(kbase + k_rowoff + 8) * THREE_D,
                kls_w + 512);
    gload_lds16(vg_base + (size_t)(kbase + v_rowoff) * THREE_D +
                    16 * ((2 * w + 0) & 3), vls_w);
    gload_lds16(vg_base + (size_t)(kbase + v_rowoff) * THREE_D +
                    16 * ((2 * w + 1) & 3), vls_w + 512);
    __syncthreads();  // includes vmcnt(0): tiles resident

    // ---- S = Q K^T : 8 MFMA
    f32x4 sa[4] = {};
    const char* kbytes = (const char*)Kls;
#pragma unroll
    for (int s = 0; s < 2; ++s) {
      const short8 qf = s ? qf1 : qf0;
#pragma unroll
      for (int n = 0; n < 4; ++n) {
        const int baddr =
            (((16 * n + q) * 128 + 64 * s + 16 * g)) ^ ((q & 7) << 4);
        const short8 kf = *reinterpret_cast<const short8*>(kbytes + baddr);
        sa[n] = __builtin_amdgcn_mfma_f32_16x16x32_bf16(qf, kf, sa[n], 0, 0, 0);
      }
    }

    // ---- anti-local mask (only ~2/32 tiles overlap the band)
    if (kbase + 64 > qlo - half && kbase < qlo + 15 + half) {
#pragma unroll
      for (int n = 0; n < 4; ++n) {
        const int j = kbase + 16 * n + q;
#pragma unroll
        for (int r = 0; r < 4; ++r) {
          const int i = qlo + 4 * g + r;
          if (j >= i - half && j < i + half) sa[n][r] = -1e30f;
        }
      }
    }

    // ---- online softmax (row = 4g + r, 16 lanes/row)
#pragma unroll
    for (int r = 0; r < 4; ++r) {
      float mx = fmaxf(fmaxf(sa[0][r], sa[1][r]), fmaxf(sa[2][r], sa[3][r]));
      mx = fmaxf(mx, __shfl_xor(mx, 1, 16));
      mx = fmaxf(mx, __shfl_xor(mx, 2, 16));
      mx = fmaxf(mx, __shfl_xor(mx, 4, 16));
      mx = fmaxf(mx, __shfl_xor(mx, 8, 16));
      const float mnew = fmaxf(mrow[r], mx);
      const float corr = __expf(mrow[r] - mnew);
      mrow[r] = mnew;
      float p0 = __expf(sa[0][r] - mnew);
      float p1 = __expf(sa[1][r] - mnew);
      float p2 = __expf(sa[2][r] - mnew);
      float p3 = __expf(sa[3][r] - mnew);
      sa[0][r] = p0; sa[1][r] = p1; sa[2][r] = p2; sa[3][r] = p3;
      float ls = (p0 + p1) + (p2 + p3);
      ls += __shfl_xor(ls, 1, 16);
      ls += __shfl_xor(ls, 2, 16);
      ls += __shfl_xor(ls, 4, 16);
      ls += __shfl_xor(ls, 8, 16);
      lrow[r] = lrow[r] * corr + ls;
#pragma unroll
      for (int n = 0; n < 4; ++n) oacc[n][r] *= corr;
    }

    // ---- P -> LDS (col-major [k][q], packed bf16 pairs)
#pragma unroll
    for (int n = 0; n < 4; ++n) {
      uint2 pk;
      pk.x = (unsigned)f2bf(sa[n][0]) | ((unsigned)f2bf(sa[n][1]) << 16);
      pk.y = (unsigned)f2bf(sa[n][2]) | ((unsigned)f2bf(sa[n][3]) << 16);
      *reinterpret_cast<uint2*>((char*)pw + (16 * n + q) * 32 + 8 * g) = pk;
    }
    asm volatile("s_waitcnt lgkmcnt(0)" ::: "memory");  // P visible to DS pipe

    // ---- O += P V : tr-read A (P) and B (V) frags, 8 MFMA
#pragma unroll
    for (int s = 0; s < 2; ++s) {
      short4v plo, phi, vlo[4], vhi[4];
      {
        const __attribute__((address_space(3))) unsigned short* pa =
            (const __attribute__((address_space(3))) unsigned short*)(
                (char*)pw + 1024 * s + 256 * g + 8 * q);
        asm volatile("ds_read_b64_tr_b16 %0, %1 offset:0" : "=v"(plo) : "v"(pa));
        asm volatile("ds_read_b64_tr_b16 %0, %1 offset:128" : "=v"(phi) : "v"(pa));
      }
#pragma unroll
      for (int n = 0; n < 4; ++n) {
        const __attribute__((address_space(3))) unsigned short* va =
            (const __attribute__((address_space(3))) unsigned short*)(
                (char*)Vls + 4096 * s + 1024 * n + 256 * g + 8 * q);
        asm volatile("ds_read_b64_tr_b16 %0, %1 offset:0" : "=v"(vlo[n]) : "v"(va));
        asm volatile("ds_read_b64_tr_b16 %0, %1 offset:128" : "=v"(vhi[n]) : "v"(va));
      }
      // wait for all tr reads; tie results so nothing consumes early
      asm volatile("s_waitcnt lgkmcnt(0)"
                   : "+v"(plo), "+v"(phi), "+v"(vlo[0]), "+v"(vhi[0]),
                     "+v"(vlo[1]), "+v"(vhi[1]), "+v"(vlo[2]), "+v"(vhi[2]),
                     "+v"(vlo[3]), "+v"(vhi[3])
                   :
                   : "memory");
      __builtin_amdgcn_sched_barrier(0);
      const short8 pf =
          __builtin_shufflevector(plo, phi, 0, 1, 2, 3, 4, 5, 6, 7);
#pragma unroll
      for (int n = 0; n < 4; ++n) {
        const short8 vf =
            __builtin_shufflevector(vlo[n], vhi[n], 0, 1, 2, 3, 4, 5, 6, 7);
        oacc[n] = __builtin_amdgcn_mfma_f32_16x16x32_bf16(pf, vf, oacc[n], 0, 0, 0);
      }
    }
  }

  // ---- epilogue: O / l -> ctx[b, row, h*64 + d]  (C-frag row = 4g + r)
#pragma unroll
  for (int r = 0; r < 4; ++r) {
    const float inv = 1.0f / lrow[r];
    const int row = qbase + w * 16 + 4 * g + r;
    float* crow = ctx + ((size_t)(b * Ll + row)) * Dd + h * 64 + q;
#pragma unroll
    for (int n = 0; n < 4; ++n) crow[16 * n] = oacc[n][r] * inv;
  }
}

// ---------------------------------------------------------------------------
// GEMM2 (fp32): y = ctx @ out_proj_w^T + b + x   (residual fused)
// ---------------------------------------------------------------------------
__global__ __launch_bounds__(256) void gemm_out(
    const float* __restrict__ A, const float* __restrict__ W,
    const float* __restrict__ bias, const float* __restrict__ R,
    float* __restrict__ C) {
  constexpr int K = 512, N = 512;
  __shared__ float As[64][68];
  __shared__ float Ws[64][68];

  const int tid = threadIdx.x;
  const int tx = tid & 15;
  const int ty = tid >> 4;
  const int m0 = blockIdx.y * 64;
  const int n0 = blockIdx.x * 64;

  float acc[4][4] = {};

  for (int k0 = 0; k0 < K; k0 += 64) {
#pragma unroll
    for (int p = 0; p < 4; ++p) {
      const int row = ty + p * 16;
      const int col = tx * 4;
      float4 a = *reinterpret_cast<const float4*>(
          &A[(size_t)(m0 + row) * K + k0 + col]);
      float4 w = *reinterpret_cast<const float4*>(
          &W[(size_t)(n0 + row) * K + k0 + col]);
      As[col + 0][row] = a.x; As[col + 1][row] = a.y;
      As[col + 2][row] = a.z; As[col + 3][row] = a.w;
      Ws[col + 0][row] = w.x; Ws[col + 1][row] = w.y;
      Ws[col + 2][row] = w.z; Ws[col + 3][row] = w.w;
    }
    __syncthreads();
#pragma unroll 8
    for (int kk = 0; kk < 64; ++kk) {
      float4 a4 = *reinterpret_cast<const float4*>(&As[kk][ty * 4]);
      float4 w4 = *reinterpret_cast<const float4*>(&Ws[kk][tx * 4]);
      const float av[4] = {a4.x, a4.y, a4.z, a4.w};
      const float wv[4] = {w4.x, w4.y, w4.z, w4.w};
#pragma unroll
      for (int r = 0; r < 4; ++r)
#pragma unroll
        for (int c = 0; c < 4; ++c) acc[r][c] = fmaf(av[r], wv[c], acc[r][c]);
    }
    __syncthreads();
  }

#pragma unroll
  for (int r = 0; r < 4; ++r) {
    const int m = m0 + ty * 4 + r;
#pragma unroll
    for (int c = 0; c < 4; ++c) {
      const int n = n0 + tx * 4 + c;
      C[(size_t)m * N + n] = acc[r][c] + bias[n] + R[(size_t)m * N + n];
    }
  }
}

// ---------------------------------------------------------------------------
// Row LayerNorm
// ---------------------------------------------------------------------------
__global__ __launch_bounds__(256) void ln_kernel(
    const float* __restrict__ y, const float* __restrict__ gamma,
    const float* __restrict__ beta, float* __restrict__ out) {
  const int row = blockIdx.x;
  const int tid = threadIdx.x;
  const float* yr = y + (size_t)row * Dd;

  float2 v = *reinterpret_cast<const float2*>(&yr[tid * 2]);
  float s = v.x + v.y;
  float qq = v.x * v.x + v.y * v.y;
#pragma unroll
  for (int off = 1; off < 64; off <<= 1) {
    s += __shfl_xor(s, off, 64);
    qq += __shfl_xor(qq, off, 64);
  }
  __shared__ float ss[4], qs[4];
  if ((tid & 63) == 0) { ss[tid >> 6] = s; qs[tid >> 6] = qq; }
  __syncthreads();
  s = (ss[0] + ss[1]) + (ss[2] + ss[3]);
  qq = (qs[0] + qs[1]) + (qs[2] + qs[3]);

  const float mu = s * (1.0f / Dd);
  const float var = qq * (1.0f / Dd) - mu * mu;
  const float rstd = rsqrtf(var + 1e-5f);

  float2 gmv = *reinterpret_cast<const float2*>(&gamma[tid * 2]);
  float2 bev = *reinterpret_cast<const float2*>(&beta[tid * 2]);
  float2 o;
  o.x = (v.x - mu) * rstd * gmv.x + bev.x;
  o.y = (v.y - mu) * rstd * gmv.y + bev.y;
  *reinterpret_cast<float2*>(&out[(size_t)row * Dd + tid * 2]) = o;
}

}  // namespace

extern "C" void kernel_launch(void* const* d_in, const int* in_sizes, int n_in,
                              void* d_out, int out_size, void* d_ws,
                              size_t ws_size, hipStream_t stream) {
  const float* x = (const float*)d_in[0];
  const float* w_in = (const float*)d_in[1];
  const float* b_in = (const float*)d_in[2];
  const float* w_out = (const float*)d_in[3];
  const float* b_out = (const float*)d_in[4];
  const float* gamma = (const float*)d_in[5];
  const float* beta = (const float*)d_in[6];
  const int* wsz = (const int*)d_in[7];
  float* out = (float*)d_out;

  unsigned short* qkvb = (unsigned short*)d_ws;              // 12.6 MB bf16
  float* ctx = (float*)((char*)d_ws + (size_t)M * THREE_D * 2);  // 8.4 MB
  float* y = (float*)d_ws;  // reuse qkv region (dead after attention)

  dim3 blk(256);

  gemm_qkv<<<dim3(THREE_D / 64, M / 64), blk, 0, stream>>>(x, w_in, b_in,
                                                           qkvb);
  attn_mfma<<<dim3(Bb * Hh * (Ll / 64)), blk, 0, stream>>>(qkvb, wsz, ctx);
  gemm_out<<<dim3(Dd / 64, M / 64), blk, 0, stream>>>(ctx, w_out, b_out, x, y);
  ln_kernel<<<dim3(M), blk, 0, stream>>>(y, gamma, beta, out);
}

// Round 3
// 110.171 us; speedup vs baseline: 3.9494x; 2.0306x over previous
//
#include <hip/hip_runtime.h>
#include <hip/hip_bf16.h>
#include <math.h>

namespace {

constexpr int Bb = 2, Ll = 2048, Dd = 512, Hh = 8;
constexpr int M = Bb * Ll;       // 4096
constexpr int THREE_D = 3 * Dd;  // 1536

typedef __attribute__((ext_vector_type(8))) short short8;
typedef __attribute__((ext_vector_type(4))) short short4v;
typedef __attribute__((ext_vector_type(4))) float f32x4;

__device__ __forceinline__ unsigned short f2bf(float x) {
  union { __hip_bfloat16 h; unsigned short u; } cv;
  cv.h = __float2bfloat16(x);
  return cv.u;
}

__device__ __forceinline__ void gload_lds16(const void* g, void* l) {
  __builtin_amdgcn_global_load_lds(
      (const __attribute__((address_space(1))) void*)g,
      (__attribute__((address_space(3))) void*)l, 16, 0, 0);
}

// ---------------------------------------------------------------------------
// fp32 -> bf16 conversion for x, in_proj_w, out_proj_w (one fused kernel)
// ---------------------------------------------------------------------------
constexpr int QUADS_X = (M * Dd) / 4;        // 524288
constexpr int QUADS_W1 = (THREE_D * Dd) / 4; // 196608
constexpr int QUADS_W2 = (Dd * Dd) / 4;      // 65536
constexpr int QUADS_TOT = QUADS_X + QUADS_W1 + QUADS_W2;

__global__ __launch_bounds__(256) void cvt_bf16(
    const float* __restrict__ x, const float* __restrict__ w1,
    const float* __restrict__ w2, unsigned short* __restrict__ xb,
    unsigned short* __restrict__ wb, unsigned short* __restrict__ wob) {
  const int i = blockIdx.x * 256 + threadIdx.x;
  const float* src;
  unsigned short* dst;
  if (i < QUADS_X) {
    src = x + 4 * (size_t)i;
    dst = xb + 4 * (size_t)i;
  } else if (i < QUADS_X + QUADS_W1) {
    const int j = i - QUADS_X;
    src = w1 + 4 * (size_t)j;
    dst = wb + 4 * (size_t)j;
  } else {
    const int j = i - (QUADS_X + QUADS_W1);
    src = w2 + 4 * (size_t)j;
    dst = wob + 4 * (size_t)j;
  }
  float4 v = *reinterpret_cast<const float4*>(src);
  ushort4 o;
  o.x = f2bf(v.x); o.y = f2bf(v.y); o.z = f2bf(v.z); o.w = f2bf(v.w);
  *reinterpret_cast<ushort4*>(dst) = o;
}

// ---------------------------------------------------------------------------
// MFMA GEMM: C[M,N] = A[M,K] @ B[N,K]^T (+bias)(+residual), bf16 in, fp32 acc.
// 128x128 tile, BK=64, 4 waves x 64x64, global_load_lds w=16 with
// pre-swizzled source; ds_read_b128 with ((row&7)<<4) XOR swizzle.
// QKV: out = bf16((acc+bias)*0.125 for n<512 else acc+bias)
// else: out = fp32(acc + bias + R)
// ---------------------------------------------------------------------------
template <int K, int N, bool QKV>
__global__ __launch_bounds__(256) void gemm_mfma(
    const unsigned short* __restrict__ A, const unsigned short* __restrict__ B,
    const float* __restrict__ bias, const float* __restrict__ R,
    unsigned short* __restrict__ Cb, float* __restrict__ Cf) {
  __shared__ unsigned short As[128 * 64];
  __shared__ unsigned short Bs[128 * 64];

  const int tid = threadIdx.x;
  const int lane = tid & 63;
  const int wu = __builtin_amdgcn_readfirstlane(tid >> 6);
  const int q = lane & 15;
  const int g = lane >> 4;
  const int wr = wu >> 1, wc = wu & 1;
  const int m0 = blockIdx.y * 128, n0 = blockIdx.x * 128;

  // staging: wave wu, load i covers rows 32*wu+8*i .. +7 (128B each);
  // source col pre-swizzled so LDS[row][blk] = G[row][blk ^ (row&7)]
  const int srow = lane >> 3;
  const int scol = 8 * ((lane & 7) ^ srow);
  const unsigned short* Ag = A + (size_t)(m0 + 32 * wu + srow) * K + scol;
  const unsigned short* Bg = B + (size_t)(n0 + 32 * wu + srow) * K + scol;
  char* AsW = (char*)As + wu * 4096;
  char* BsW = (char*)Bs + wu * 4096;

  f32x4 acc[4][4] = {};

  for (int k0 = 0; k0 < K; k0 += 64) {
    __syncthreads();  // previous tile's readers done
#pragma unroll
    for (int i = 0; i < 4; ++i) {
      gload_lds16(Ag + (size_t)(8 * i) * K + k0, AsW + 1024 * i);
      gload_lds16(Bg + (size_t)(8 * i) * K + k0, BsW + 1024 * i);
    }
    __syncthreads();  // vmcnt(0) drained by barrier semantics

    const char* Abase = (const char*)As + (wr * 64 + q) * 128;
    const char* Bbase = (const char*)Bs + (wc * 64 + q) * 128;
#pragma unroll
    for (int s = 0; s < 2; ++s) {
      const int csw = (64 * s + 16 * g) ^ ((q & 7) << 4);
      short8 af[4], bf[4];
#pragma unroll
      for (int m = 0; m < 4; ++m)
        af[m] = *reinterpret_cast<const short8*>(Abase + m * 2048 + csw);
#pragma unroll
      for (int n = 0; n < 4; ++n)
        bf[n] = *reinterpret_cast<const short8*>(Bbase + n * 2048 + csw);
#pragma unroll
      for (int m = 0; m < 4; ++m)
#pragma unroll
        for (int n = 0; n < 4; ++n)
          acc[m][n] = __builtin_amdgcn_mfma_f32_16x16x32_bf16(
              af[m], bf[n], acc[m][n], 0, 0, 0);
    }
  }

  const float sc = (QKV && n0 < Dd) ? 0.125f : 1.0f;
#pragma unroll
  for (int m = 0; m < 4; ++m) {
#pragma unroll
    for (int r = 0; r < 4; ++r) {
      const int row = m0 + wr * 64 + m * 16 + 4 * g + r;
#pragma unroll
      for (int n = 0; n < 4; ++n) {
        const int col = n0 + wc * 64 + n * 16 + q;
        const float v = acc[m][n][r] + bias[col];
        if (QKV) {
          Cb[(size_t)row * N + col] = f2bf(v * sc);
        } else {
          Cf[(size_t)row * N + col] = v + R[(size_t)row * N + col];
        }
      }
    }
  }
}

// ---------------------------------------------------------------------------
// MFMA flash attention (unchanged from round 2 except bf16 ctx output).
// ---------------------------------------------------------------------------
__global__ __launch_bounds__(256) void attn_mfma(
    const unsigned short* __restrict__ qkv, const int* __restrict__ wsz,
    unsigned short* __restrict__ ctx) {
  __shared__ unsigned short Kls[4096];
  __shared__ unsigned short Vls[4096];
  __shared__ unsigned short Pls[4096];

  const int tid = threadIdx.x;
  const int lane = tid & 63;
  const int w = tid >> 6;
  const int wu = __builtin_amdgcn_readfirstlane(w);
  const int q = lane & 15;
  const int g = lane >> 4;

  const int qt = blockIdx.x & 31;
  const int h = (blockIdx.x >> 5) & 7;
  const int b = blockIdx.x >> 8;
  const int qbase = qt * 64;
  const int half = wsz[0] >> 1;

  const size_t bh_base = (size_t)b * Ll * THREE_D + h * 64;

  const unsigned short* qrow =
      qkv + bh_base + (size_t)(qbase + w * 16 + q) * THREE_D;
  const short8 qf0 = *reinterpret_cast<const short8*>(qrow + 8 * g);
  const short8 qf1 = *reinterpret_cast<const short8*>(qrow + 32 + 8 * g);

  const int k_rowoff = w * 16 + (lane >> 3);
  const int k_dcol = 8 * ((lane & 7) ^ ((lane >> 3) & 7));
  const unsigned short* kg_base = qkv + bh_base + Dd + k_dcol;

  const int v_rowoff = 32 * (w >> 1) + 8 * ((lane >> 4) & 3) +
                       4 * ((lane >> 3) & 1) + ((lane >> 1) & 3);
  const unsigned short* vg_base = qkv + bh_base + 2 * Dd + 8 * (lane & 1);

  unsigned short* kls_w = &Kls[wu * 1024];
  unsigned short* vls_w = &Vls[wu * 1024];
  unsigned short* pw = &Pls[wu * 1024];

  f32x4 oacc[4] = {};
  float mrow[4], lrow[4];
#pragma unroll
  for (int r = 0; r < 4; ++r) { mrow[r] = -1e30f; lrow[r] = 0.f; }

  const int qlo = qbase + w * 16;

  for (int kt = 0; kt < Ll / 64; ++kt) {
    const int kbase = kt * 64;
    __syncthreads();

    gload_lds16(kg_base + (size_t)(kbase + k_rowoff) * THREE_D, kls_w);
    gload_lds16(kg_base + (size_t)(kbase + k_rowoff + 8) * THREE_D,
                kls_w + 512);
    gload_lds16(vg_base + (size_t)(kbase + v_rowoff) * THREE_D +
                    16 * ((2 * w + 0) & 3), vls_w);
    gload_lds16(vg_base + (size_t)(kbase + v_rowoff) * THREE_D +
                    16 * ((2 * w + 1) & 3), vls_w + 512);
    __syncthreads();

    // ---- S = Q K^T
    f32x4 sa[4] = {};
    const char* kbytes = (const char*)Kls;
#pragma unroll
    for (int s = 0; s < 2; ++s) {
      const short8 qf = s ? qf1 : qf0;
#pragma unroll
      for (int n = 0; n < 4; ++n) {
        const int baddr =
            (((16 * n + q) * 128 + 64 * s + 16 * g)) ^ ((q & 7) << 4);
        const short8 kf = *reinterpret_cast<const short8*>(kbytes + baddr);
        sa[n] = __builtin_amdgcn_mfma_f32_16x16x32_bf16(qf, kf, sa[n], 0, 0, 0);
      }
    }

    // ---- anti-local mask
    if (kbase + 64 > qlo - half && kbase < qlo + 15 + half) {
#pragma unroll
      for (int n = 0; n < 4; ++n) {
        const int j = kbase + 16 * n + q;
#pragma unroll
        for (int r = 0; r < 4; ++r) {
          const int i = qlo + 4 * g + r;
          if (j >= i - half && j < i + half) sa[n][r] = -1e30f;
        }
      }
    }

    // ---- online softmax
#pragma unroll
    for (int r = 0; r < 4; ++r) {
      float mx = fmaxf(fmaxf(sa[0][r], sa[1][r]), fmaxf(sa[2][r], sa[3][r]));
      mx = fmaxf(mx, __shfl_xor(mx, 1, 16));
      mx = fmaxf(mx, __shfl_xor(mx, 2, 16));
      mx = fmaxf(mx, __shfl_xor(mx, 4, 16));
      mx = fmaxf(mx, __shfl_xor(mx, 8, 16));
      const float mnew = fmaxf(mrow[r], mx);
      const float corr = __expf(mrow[r] - mnew);
      mrow[r] = mnew;
      float p0 = __expf(sa[0][r] - mnew);
      float p1 = __expf(sa[1][r] - mnew);
      float p2 = __expf(sa[2][r] - mnew);
      float p3 = __expf(sa[3][r] - mnew);
      sa[0][r] = p0; sa[1][r] = p1; sa[2][r] = p2; sa[3][r] = p3;
      float ls = (p0 + p1) + (p2 + p3);
      ls += __shfl_xor(ls, 1, 16);
      ls += __shfl_xor(ls, 2, 16);
      ls += __shfl_xor(ls, 4, 16);
      ls += __shfl_xor(ls, 8, 16);
      lrow[r] = lrow[r] * corr + ls;
#pragma unroll
      for (int n = 0; n < 4; ++n) oacc[n][r] *= corr;
    }

    // ---- P -> LDS
#pragma unroll
    for (int n = 0; n < 4; ++n) {
      uint2 pk;
      pk.x = (unsigned)f2bf(sa[n][0]) | ((unsigned)f2bf(sa[n][1]) << 16);
      pk.y = (unsigned)f2bf(sa[n][2]) | ((unsigned)f2bf(sa[n][3]) << 16);
      *reinterpret_cast<uint2*>((char*)pw + (16 * n + q) * 32 + 8 * g) = pk;
    }
    asm volatile("s_waitcnt lgkmcnt(0)" ::: "memory");

    // ---- O += P V
#pragma unroll
    for (int s = 0; s < 2; ++s) {
      short4v plo, phi, vlo[4], vhi[4];
      {
        const __attribute__((address_space(3))) unsigned short* pa =
            (const __attribute__((address_space(3))) unsigned short*)(
                (char*)pw + 1024 * s + 256 * g + 8 * q);
        asm volatile("ds_read_b64_tr_b16 %0, %1 offset:0" : "=v"(plo) : "v"(pa));
        asm volatile("ds_read_b64_tr_b16 %0, %1 offset:128" : "=v"(phi) : "v"(pa));
      }
#pragma unroll
      for (int n = 0; n < 4; ++n) {
        const __attribute__((address_space(3))) unsigned short* va =
            (const __attribute__((address_space(3))) unsigned short*)(
                (char*)Vls + 4096 * s + 1024 * n + 256 * g + 8 * q);
        asm volatile("ds_read_b64_tr_b16 %0, %1 offset:0" : "=v"(vlo[n]) : "v"(va));
        asm volatile("ds_read_b64_tr_b16 %0, %1 offset:128" : "=v"(vhi[n]) : "v"(va));
      }
      asm volatile("s_waitcnt lgkmcnt(0)"
                   : "+v"(plo), "+v"(phi), "+v"(vlo[0]), "+v"(vhi[0]),
                     "+v"(vlo[1]), "+v"(vhi[1]), "+v"(vlo[2]), "+v"(vhi[2]),
                     "+v"(vlo[3]), "+v"(vhi[3])
                   :
                   : "memory");
      __builtin_amdgcn_sched_barrier(0);
      const short8 pf =
          __builtin_shufflevector(plo, phi, 0, 1, 2, 3, 4, 5, 6, 7);
#pragma unroll
      for (int n = 0; n < 4; ++n) {
        const short8 vf =
            __builtin_shufflevector(vlo[n], vhi[n], 0, 1, 2, 3, 4, 5, 6, 7);
        oacc[n] = __builtin_amdgcn_mfma_f32_16x16x32_bf16(pf, vf, oacc[n], 0, 0, 0);
      }
    }
  }

  // ---- epilogue: bf16 ctx
#pragma unroll
  for (int r = 0; r < 4; ++r) {
    const float inv = 1.0f / lrow[r];
    const int row = qbase + w * 16 + 4 * g + r;
    unsigned short* crow = ctx + ((size_t)(b * Ll + row)) * Dd + h * 64 + q;
#pragma unroll
    for (int n = 0; n < 4; ++n) crow[16 * n] = f2bf(oacc[n][r] * inv);
  }
}

// ---------------------------------------------------------------------------
// Row LayerNorm
// ---------------------------------------------------------------------------
__global__ __launch_bounds__(256) void ln_kernel(
    const float* __restrict__ y, const float* __restrict__ gamma,
    const float* __restrict__ beta, float* __restrict__ out) {
  const int row = blockIdx.x;
  const int tid = threadIdx.x;
  const float* yr = y + (size_t)row * Dd;

  float2 v = *reinterpret_cast<const float2*>(&yr[tid * 2]);
  float s = v.x + v.y;
  float qq = v.x * v.x + v.y * v.y;
#pragma unroll
  for (int off = 1; off < 64; off <<= 1) {
    s += __shfl_xor(s, off, 64);
    qq += __shfl_xor(qq, off, 64);
  }
  __shared__ float ss[4], qs[4];
  if ((tid & 63) == 0) { ss[tid >> 6] = s; qs[tid >> 6] = qq; }
  __syncthreads();
  s = (ss[0] + ss[1]) + (ss[2] + ss[3]);
  qq = (qs[0] + qs[1]) + (qs[2] + qs[3]);

  const float mu = s * (1.0f / Dd);
  const float var = qq * (1.0f / Dd) - mu * mu;
  const float rstd = rsqrtf(var + 1e-5f);

  float2 gmv = *reinterpret_cast<const float2*>(&gamma[tid * 2]);
  float2 bev = *reinterpret_cast<const float2*>(&beta[tid * 2]);
  float2 o;
  o.x = (v.x - mu) * rstd * gmv.x + bev.x;
  o.y = (v.y - mu) * rstd * gmv.y + bev.y;
  *reinterpret_cast<float2*>(&out[(size_t)row * Dd + tid * 2]) = o;
}

}  // namespace

extern "C" void kernel_launch(void* const* d_in, const int* in_sizes, int n_in,
                              void* d_out, int out_size, void* d_ws,
                              size_t ws_size, hipStream_t stream) {
  const float* x = (const float*)d_in[0];
  const float* w_in = (const float*)d_in[1];
  const float* b_in = (const float*)d_in[2];
  const float* w_out = (const float*)d_in[3];
  const float* b_out = (const float*)d_in[4];
  const float* gamma = (const float*)d_in[5];
  const float* beta = (const float*)d_in[6];
  const int* wsz = (const int*)d_in[7];
  float* out = (float*)d_out;

  unsigned short* ws16 = (unsigned short*)d_ws;
  unsigned short* qkvb = ws16;                       // 6291456 elems
  unsigned short* ctxb = ws16 + 6291456;             // 2097152
  unsigned short* xb = ws16 + 8388608;               // 2097152
  unsigned short* wb = ws16 + 10485760;              // 786432
  unsigned short* wob = ws16 + 11272192;             // 262144
  float* y = (float*)d_ws;  // aliases qkvb (dead after attention)

  dim3 blk(256);

  cvt_bf16<<<dim3(QUADS_TOT / 256), blk, 0, stream>>>(x, w_in, w_out, xb, wb,
                                                      wob);
  gemm_mfma<512, 1536, true><<<dim3(12, 32), blk, 0, stream>>>(
      xb, wb, b_in, nullptr, qkvb, nullptr);
  attn_mfma<<<dim3(512), blk, 0, stream>>>(qkvb, wsz, ctxb);
  gemm_mfma<512, 512, false><<<dim3(4, 32), blk, 0, stream>>>(
      ctxb, wob, b_out, x, nullptr, y);
  ln_kernel<<<dim3(M), blk, 0, stream>>>(y, gamma, beta, out);
}

// Round 4
// 98.722 us; speedup vs baseline: 4.4074x; 1.1160x over previous
//
#include <hip/hip_runtime.h>
#include <hip/hip_bf16.h>
#include <math.h>

namespace {

constexpr int Bb = 2, Ll = 2048, Dd = 512, Hh = 8;
constexpr int M = Bb * Ll;       // 4096
constexpr int THREE_D = 3 * Dd;  // 1536

typedef __attribute__((ext_vector_type(8))) short short8;
typedef __attribute__((ext_vector_type(4))) short short4v;
typedef __attribute__((ext_vector_type(4))) float f32x4;

__device__ __forceinline__ unsigned short f2bf(float x) {
  union { __hip_bfloat16 h; unsigned short u; } cv;
  cv.h = __float2bfloat16(x);
  return cv.u;
}

__device__ __forceinline__ void gload_lds16(const void* g, void* l) {
  __builtin_amdgcn_global_load_lds(
      (const __attribute__((address_space(1))) void*)g,
      (__attribute__((address_space(3))) void*)l, 16, 0, 0);
}

// ---------------------------------------------------------------------------
// fp32 -> bf16 conversion for x, in_proj_w, out_proj_w (one fused kernel)
// ---------------------------------------------------------------------------
constexpr int QUADS_X = (M * Dd) / 4;        // 524288
constexpr int QUADS_W1 = (THREE_D * Dd) / 4; // 196608
constexpr int QUADS_W2 = (Dd * Dd) / 4;      // 65536
constexpr int QUADS_TOT = QUADS_X + QUADS_W1 + QUADS_W2;

__global__ __launch_bounds__(256) void cvt_bf16(
    const float* __restrict__ x, const float* __restrict__ w1,
    const float* __restrict__ w2, unsigned short* __restrict__ xb,
    unsigned short* __restrict__ wb, unsigned short* __restrict__ wob) {
  const int i = blockIdx.x * 256 + threadIdx.x;
  const float* src;
  unsigned short* dst;
  if (i < QUADS_X) {
    src = x + 4 * (size_t)i;
    dst = xb + 4 * (size_t)i;
  } else if (i < QUADS_X + QUADS_W1) {
    const int j = i - QUADS_X;
    src = w1 + 4 * (size_t)j;
    dst = wb + 4 * (size_t)j;
  } else {
    const int j = i - (QUADS_X + QUADS_W1);
    src = w2 + 4 * (size_t)j;
    dst = wob + 4 * (size_t)j;
  }
  float4 v = *reinterpret_cast<const float4*>(src);
  ushort4 o;
  o.x = f2bf(v.x); o.y = f2bf(v.y); o.z = f2bf(v.z); o.w = f2bf(v.w);
  *reinterpret_cast<ushort4*>(dst) = o;
}

// ---------------------------------------------------------------------------
// MFMA GEMM: C[M,N] = A[M,K] @ B[N,K]^T (+bias)(+residual), bf16 in, fp32 acc.
// 128x128 tile, BK=64, 4 waves x 64x64, global_load_lds w=16 with
// pre-swizzled source; ds_read_b128 with ((row&7)<<4) XOR swizzle.
// ---------------------------------------------------------------------------
template <int K, int N, bool QKV>
__global__ __launch_bounds__(256) void gemm_mfma(
    const unsigned short* __restrict__ A, const unsigned short* __restrict__ B,
    const float* __restrict__ bias, const float* __restrict__ R,
    unsigned short* __restrict__ Cb, float* __restrict__ Cf) {
  __shared__ unsigned short As[128 * 64];
  __shared__ unsigned short Bs[128 * 64];

  const int tid = threadIdx.x;
  const int lane = tid & 63;
  const int wu = __builtin_amdgcn_readfirstlane(tid >> 6);
  const int q = lane & 15;
  const int g = lane >> 4;
  const int wr = wu >> 1, wc = wu & 1;
  const int m0 = blockIdx.y * 128, n0 = blockIdx.x * 128;

  const int srow = lane >> 3;
  const int scol = 8 * ((lane & 7) ^ srow);
  const unsigned short* Ag = A + (size_t)(m0 + 32 * wu + srow) * K + scol;
  const unsigned short* Bg = B + (size_t)(n0 + 32 * wu + srow) * K + scol;
  char* AsW = (char*)As + wu * 4096;
  char* BsW = (char*)Bs + wu * 4096;

  f32x4 acc[4][4] = {};

  for (int k0 = 0; k0 < K; k0 += 64) {
    __syncthreads();
#pragma unroll
    for (int i = 0; i < 4; ++i) {
      gload_lds16(Ag + (size_t)(8 * i) * K + k0, AsW + 1024 * i);
      gload_lds16(Bg + (size_t)(8 * i) * K + k0, BsW + 1024 * i);
    }
    __syncthreads();

    const char* Abase = (const char*)As + (wr * 64 + q) * 128;
    const char* Bbase = (const char*)Bs + (wc * 64 + q) * 128;
#pragma unroll
    for (int s = 0; s < 2; ++s) {
      const int csw = (64 * s + 16 * g) ^ ((q & 7) << 4);
      short8 af[4], bf[4];
#pragma unroll
      for (int m = 0; m < 4; ++m)
        af[m] = *reinterpret_cast<const short8*>(Abase + m * 2048 + csw);
#pragma unroll
      for (int n = 0; n < 4; ++n)
        bf[n] = *reinterpret_cast<const short8*>(Bbase + n * 2048 + csw);
#pragma unroll
      for (int m = 0; m < 4; ++m)
#pragma unroll
        for (int n = 0; n < 4; ++n)
          acc[m][n] = __builtin_amdgcn_mfma_f32_16x16x32_bf16(
              af[m], bf[n], acc[m][n], 0, 0, 0);
    }
  }

  const float sc = (QKV && n0 < Dd) ? 0.125f : 1.0f;
#pragma unroll
  for (int m = 0; m < 4; ++m) {
#pragma unroll
    for (int r = 0; r < 4; ++r) {
      const int row = m0 + wr * 64 + m * 16 + 4 * g + r;
#pragma unroll
      for (int n = 0; n < 4; ++n) {
        const int col = n0 + wc * 64 + n * 16 + q;
        const float v = acc[m][n][r] + bias[col];
        if (QKV) {
          Cb[(size_t)row * N + col] = f2bf(v * sc);
        } else {
          Cf[(size_t)row * N + col] = v + R[(size_t)row * N + col];
        }
      }
    }
  }
}

// ---------------------------------------------------------------------------
// MFMA flash attention with in-block kv-split.
// Block = (b, h, 64 q-rows), 8 waves (512 threads):
//   wave w: q-rows 16*(w&3)..+15, kv half hv = w>>2 (tiles hv*16..hv*16+15).
// Per-tile math identical to round-3 verified version; final in-LDS merge
// combines the two (m,l,O) partials exactly.
// ---------------------------------------------------------------------------
__global__ __launch_bounds__(512) void attn_mfma(
    const unsigned short* __restrict__ qkv, const int* __restrict__ wsz,
    unsigned short* __restrict__ ctx) {
  __shared__ unsigned short Kls[8192];  // 2 groups x 4KB
  __shared__ unsigned short Vls[8192];
  __shared__ unsigned short Pls[8192];  // per-wave 1KB

  const int tid = threadIdx.x;
  const int lane = tid & 63;
  const int w = tid >> 6;
  const int wu = __builtin_amdgcn_readfirstlane(w);
  const int wg = w & 3;    // q sub-tile within group
  const int hv = w >> 2;   // kv half
  const int q = lane & 15;
  const int g = lane >> 4;

  const int qt = blockIdx.x & 31;
  const int h = (blockIdx.x >> 5) & 7;
  const int b = blockIdx.x >> 8;
  const int qbase = qt * 64;
  const int hwin = wsz[0] >> 1;

  const size_t bh_base = (size_t)b * Ll * THREE_D + h * 64;

  const unsigned short* qrow =
      qkv + bh_base + (size_t)(qbase + wg * 16 + q) * THREE_D;
  const short8 qf0 = *reinterpret_cast<const short8*>(qrow + 8 * g);
  const short8 qf1 = *reinterpret_cast<const short8*>(qrow + 32 + 8 * g);

  const int k_rowoff = wg * 16 + (lane >> 3);
  const int k_dcol = 8 * ((lane & 7) ^ ((lane >> 3) & 7));
  const unsigned short* kg_base = qkv + bh_base + Dd + k_dcol;

  const int v_rowoff = 32 * (wg >> 1) + 8 * ((lane >> 4) & 3) +
                       4 * ((lane >> 3) & 1) + ((lane >> 1) & 3);
  const unsigned short* vg_base = qkv + bh_base + 2 * Dd + 8 * (lane & 1);

  unsigned short* kls_w = &Kls[wu * 1024];
  unsigned short* vls_w = &Vls[wu * 1024];
  unsigned short* pw = &Pls[wu * 1024];
  const char* kbytes = (const char*)Kls + 8192 * hv;
  const char* vbytes = (const char*)Vls + 8192 * hv;

  f32x4 oacc[4] = {};
  float mrow[4], lrow[4];
#pragma unroll
  for (int r = 0; r < 4; ++r) { mrow[r] = -1e30f; lrow[r] = 0.f; }

  const int qlo = qbase + wg * 16;

  for (int t = 0; t < 16; ++t) {
    const int kbase = (hv * 16 + t) * 64;
    __syncthreads();

    gload_lds16(kg_base + (size_t)(kbase + k_rowoff) * THREE_D, kls_w);
    gload_lds16(kg_base + (size_t)(kbase + k_rowoff + 8) * THREE_D,
                kls_w + 512);
    gload_lds16(vg_base + (size_t)(kbase + v_rowoff) * THREE_D +
                    16 * ((2 * wg + 0) & 3), vls_w);
    gload_lds16(vg_base + (size_t)(kbase + v_rowoff) * THREE_D +
                    16 * ((2 * wg + 1) & 3), vls_w + 512);
    __syncthreads();

    // ---- S = Q K^T
    f32x4 sa[4] = {};
#pragma unroll
    for (int s = 0; s < 2; ++s) {
      const short8 qf = s ? qf1 : qf0;
#pragma unroll
      for (int n = 0; n < 4; ++n) {
        const int baddr =
            (((16 * n + q) * 128 + 64 * s + 16 * g)) ^ ((q & 7) << 4);
        const short8 kf = *reinterpret_cast<const short8*>(kbytes + baddr);
        sa[n] = __builtin_amdgcn_mfma_f32_16x16x32_bf16(qf, kf, sa[n], 0, 0, 0);
      }
    }

    // ---- anti-local mask
    if (kbase + 64 > qlo - hwin && kbase < qlo + 15 + hwin) {
#pragma unroll
      for (int n = 0; n < 4; ++n) {
        const int j = kbase + 16 * n + q;
#pragma unroll
        for (int r = 0; r < 4; ++r) {
          const int i = qlo + 4 * g + r;
          if (j >= i - hwin && j < i + hwin) sa[n][r] = -1e30f;
        }
      }
    }

    // ---- online softmax
#pragma unroll
    for (int r = 0; r < 4; ++r) {
      float mx = fmaxf(fmaxf(sa[0][r], sa[1][r]), fmaxf(sa[2][r], sa[3][r]));
      mx = fmaxf(mx, __shfl_xor(mx, 1, 16));
      mx = fmaxf(mx, __shfl_xor(mx, 2, 16));
      mx = fmaxf(mx, __shfl_xor(mx, 4, 16));
      mx = fmaxf(mx, __shfl_xor(mx, 8, 16));
      const float mnew = fmaxf(mrow[r], mx);
      const float corr = __expf(mrow[r] - mnew);
      mrow[r] = mnew;
      float p0 = __expf(sa[0][r] - mnew);
      float p1 = __expf(sa[1][r] - mnew);
      float p2 = __expf(sa[2][r] - mnew);
      float p3 = __expf(sa[3][r] - mnew);
      sa[0][r] = p0; sa[1][r] = p1; sa[2][r] = p2; sa[3][r] = p3;
      float ls = (p0 + p1) + (p2 + p3);
      ls += __shfl_xor(ls, 1, 16);
      ls += __shfl_xor(ls, 2, 16);
      ls += __shfl_xor(ls, 4, 16);
      ls += __shfl_xor(ls, 8, 16);
      lrow[r] = lrow[r] * corr + ls;
#pragma unroll
      for (int n = 0; n < 4; ++n) oacc[n][r] *= corr;
    }

    // ---- P -> LDS (per-wave buffer)
#pragma unroll
    for (int n = 0; n < 4; ++n) {
      uint2 pk;
      pk.x = (unsigned)f2bf(sa[n][0]) | ((unsigned)f2bf(sa[n][1]) << 16);
      pk.y = (unsigned)f2bf(sa[n][2]) | ((unsigned)f2bf(sa[n][3]) << 16);
      *reinterpret_cast<uint2*>((char*)pw + (16 * n + q) * 32 + 8 * g) = pk;
    }
    asm volatile("s_waitcnt lgkmcnt(0)" ::: "memory");

    // ---- O += P V
#pragma unroll
    for (int s = 0; s < 2; ++s) {
      short4v plo, phi, vlo[4], vhi[4];
      {
        const __attribute__((address_space(3))) unsigned short* pa =
            (const __attribute__((address_space(3))) unsigned short*)(
                (char*)pw + 1024 * s + 256 * g + 8 * q);
        asm volatile("ds_read_b64_tr_b16 %0, %1 offset:0" : "=v"(plo) : "v"(pa));
        asm volatile("ds_read_b64_tr_b16 %0, %1 offset:128" : "=v"(phi) : "v"(pa));
      }
#pragma unroll
      for (int n = 0; n < 4; ++n) {
        const __attribute__((address_space(3))) unsigned short* va =
            (const __attribute__((address_space(3))) unsigned short*)(
                vbytes + 4096 * s + 1024 * n + 256 * g + 8 * q);
        asm volatile("ds_read_b64_tr_b16 %0, %1 offset:0" : "=v"(vlo[n]) : "v"(va));
        asm volatile("ds_read_b64_tr_b16 %0, %1 offset:128" : "=v"(vhi[n]) : "v"(va));
      }
      asm volatile("s_waitcnt lgkmcnt(0)"
                   : "+v"(plo), "+v"(phi), "+v"(vlo[0]), "+v"(vhi[0]),
                     "+v"(vlo[1]), "+v"(vhi[1]), "+v"(vlo[2]), "+v"(vhi[2]),
                     "+v"(vlo[3]), "+v"(vhi[3])
                   :
                   : "memory");
      __builtin_amdgcn_sched_barrier(0);
      const short8 pf =
          __builtin_shufflevector(plo, phi, 0, 1, 2, 3, 4, 5, 6, 7);
#pragma unroll
      for (int n = 0; n < 4; ++n) {
        const short8 vf =
            __builtin_shufflevector(vlo[n], vhi[n], 0, 1, 2, 3, 4, 5, 6, 7);
        oacc[n] = __builtin_amdgcn_mfma_f32_16x16x32_bf16(pf, vf, oacc[n], 0, 0, 0);
      }
    }
  }

  // ---- merge the two kv-half partials (exact flash combine), write ctx.
  // Alias dead K/V LDS: Om[4][16][64] f32 (16KB) over Kls, ml[4][16][2] over Vls.
  float* Om = (float*)Kls;
  float* mls = (float*)Vls;

  __syncthreads();  // all loop-phase LDS reads complete
  if (w >= 4) {
#pragma unroll
    for (int r = 0; r < 4; ++r) {
      const int rr = wg * 16 + 4 * g + r;
#pragma unroll
      for (int n = 0; n < 4; ++n) Om[rr * 64 + 16 * n + q] = oacc[n][r];
      if (q == 0)
        *reinterpret_cast<float2*>(&mls[rr * 2]) =
            make_float2(mrow[r], lrow[r]);
    }
  }
  __syncthreads();
  if (w < 4) {
#pragma unroll
    for (int r = 0; r < 4; ++r) {
      const int rr = wg * 16 + 4 * g + r;
      const float2 ml2 = *reinterpret_cast<const float2*>(&mls[rr * 2]);
      const float ms = fmaxf(mrow[r], ml2.x);
      const float c1 = __expf(mrow[r] - ms);
      const float c2 = __expf(ml2.x - ms);
      const float inv = 1.0f / (c1 * lrow[r] + c2 * ml2.y);
      const int row = qbase + rr;
      unsigned short* crow = ctx + ((size_t)(b * Ll + row)) * Dd + h * 64 + q;
#pragma unroll
      for (int n = 0; n < 4; ++n) {
        const float o2 = Om[rr * 64 + 16 * n + q];
        crow[16 * n] = f2bf((c1 * oacc[n][r] + c2 * o2) * inv);
      }
    }
  }
}

// ---------------------------------------------------------------------------
// Row LayerNorm
// ---------------------------------------------------------------------------
__global__ __launch_bounds__(256) void ln_kernel(
    const float* __restrict__ y, const float* __restrict__ gamma,
    const float* __restrict__ beta, float* __restrict__ out) {
  const int row = blockIdx.x;
  const int tid = threadIdx.x;
  const float* yr = y + (size_t)row * Dd;

  float2 v = *reinterpret_cast<const float2*>(&yr[tid * 2]);
  float s = v.x + v.y;
  float qq = v.x * v.x + v.y * v.y;
#pragma unroll
  for (int off = 1; off < 64; off <<= 1) {
    s += __shfl_xor(s, off, 64);
    qq += __shfl_xor(qq, off, 64);
  }
  __shared__ float ss[4], qs[4];
  if ((tid & 63) == 0) { ss[tid >> 6] = s; qs[tid >> 6] = qq; }
  __syncthreads();
  s = (ss[0] + ss[1]) + (ss[2] + ss[3]);
  qq = (qs[0] + qs[1]) + (qs[2] + qs[3]);

  const float mu = s * (1.0f / Dd);
  const float var = qq * (1.0f / Dd) - mu * mu;
  const float rstd = rsqrtf(var + 1e-5f);

  float2 gmv = *reinterpret_cast<const float2*>(&gamma[tid * 2]);
  float2 bev = *reinterpret_cast<const float2*>(&beta[tid * 2]);
  float2 o;
  o.x = (v.x - mu) * rstd * gmv.x + bev.x;
  o.y = (v.y - mu) * rstd * gmv.y + bev.y;
  *reinterpret_cast<float2*>(&out[(size_t)row * Dd + tid * 2]) = o;
}

}  // namespace

extern "C" void kernel_launch(void* const* d_in, const int* in_sizes, int n_in,
                              void* d_out, int out_size, void* d_ws,
                              size_t ws_size, hipStream_t stream) {
  const float* x = (const float*)d_in[0];
  const float* w_in = (const float*)d_in[1];
  const float* b_in = (const float*)d_in[2];
  const float* w_out = (const float*)d_in[3];
  const float* b_out = (const float*)d_in[4];
  const float* gamma = (const float*)d_in[5];
  const float* beta = (const float*)d_in[6];
  const int* wsz = (const int*)d_in[7];
  float* out = (float*)d_out;

  unsigned short* ws16 = (unsigned short*)d_ws;
  unsigned short* qkvb = ws16;                       // 6291456 elems
  unsigned short* ctxb = ws16 + 6291456;             // 2097152
  unsigned short* xb = ws16 + 8388608;               // 2097152
  unsigned short* wb = ws16 + 10485760;              // 786432
  unsigned short* wob = ws16 + 11272192;             // 262144
  float* y = (float*)d_ws;  // aliases qkvb (dead after attention)

  dim3 blk(256);

  cvt_bf16<<<dim3(QUADS_TOT / 256), blk, 0, stream>>>(x, w_in, w_out, xb, wb,
                                                      wob);
  gemm_mfma<512, 1536, true><<<dim3(12, 32), blk, 0, stream>>>(
      xb, wb, b_in, nullptr, qkvb, nullptr);
  attn_mfma<<<dim3(512), dim3(512), 0, stream>>>(qkvb, wsz, ctxb);
  gemm_mfma<512, 512, false><<<dim3(4, 32), blk, 0, stream>>>(
      ctxb, wob, b_out, x, nullptr, y);
  ln_kernel<<<dim3(M), blk, 0, stream>>>(y, gamma, beta, out);
}